// Round 7
// baseline (218.662 us; speedup 1.0000x reference)
//
#include <hip/hip_runtime.h>
#include <hip/hip_bf16.h>

// LocalAttention B=4, L=2048, C=512, H=8, Dh=64 — round 13.
// vs round 12 (which still spilled ~60MB: WRITE_SIZE 68MB, VGPR capped 64):
//  * K/V (attn) and A/B (proj) staged via __builtin_amdgcn_global_load_lds
//    (async DMA, no staging registers, no ds_write). LDS tiles are unpadded
//    [k-chunk][row] 16B chunks: DMA writes lane-linear (conflict-free) and
//    fragment reads are half-wave-contiguous 512B (bank-even), affine
//    offset:imm addressing.
//  * attn: softmax fused per-16-key group with its 2 PV MFMAs (pfrag
//    liveness 16->4 regs, p 16->8); mask ballot computed in-loop from a
//    one-tile-early global load (mwS LDS dropped). LDS = Q 16K + K 2x8K +
//    V 2x8K per half = 81920 B exactly -> 2 blocks/CU, 4 waves/SIMD,
//    register demand ~105 < 128 cap.
//  * proj: m97 structure — single-buffered 32.5KB LDS, gload_lds staging,
//    2 barriers/K-step, __launch_bounds__(256,3) -> 3 blocks/CU co-schedule.

#define BB  4
#define LL  2048
#define CC  512
#define HH  8
#define DHH 64

typedef __attribute__((ext_vector_type(8)))  short bf16x8;   // 16 B
typedef __attribute__((ext_vector_type(4)))  short bf16x4;   // 8 B
typedef __attribute__((ext_vector_type(16))) float f32x16;   // MFMA C/D
typedef __attribute__((ext_vector_type(2)))  unsigned uint2v;
typedef __attribute__((ext_vector_type(4)))  unsigned uint4v;

using us = unsigned short;

#if __has_builtin(__builtin_amdgcn_exp2f)
#define EXP2(x) __builtin_amdgcn_exp2f(x)
#else
#define EXP2(x) __expf(0.6931471805599453f * (x))
#endif

__device__ __forceinline__ us f2bu(float x) {   // scalar fp32->bf16 (RNE)
    unsigned u = __float_as_uint(x);
    return (us)((u + 0x7FFFu + ((u >> 16) & 1u)) >> 16);
}
// HW packed fp32->bf16 (RNE), a -> low half, b -> high half
__device__ __forceinline__ unsigned pk2(float a, float b) {
    unsigned r;
    asm("v_cvt_pk_bf16_f32 %0, %1, %2" : "=v"(r) : "v"(a), "v"(b));
    return r;
}
__device__ __forceinline__ bf16x4 pk4(float a, float b, float c, float d) {
    uint2v u; u[0] = pk2(a, b); u[1] = pk2(c, d);
    return __builtin_bit_cast(bf16x4, u);
}

// async global->LDS DMA, 16B per lane; LDS dest = wave-uniform base + lane*16
__device__ __forceinline__ void gl16(const void* g, void* l) {
    __builtin_amdgcn_global_load_lds(
        (const __attribute__((address_space(1))) unsigned int*)g,
        (__attribute__((address_space(3))) unsigned int*)l, 16, 0, 0);
}

// ---------------------------------------------------------------------------
// transpose body: fp32 [b][c][n] -> bf16 [b][n][c] for one (b, c0, n0) tile
// ---------------------------------------------------------------------------
__device__ __forceinline__ void transpose_body(const float* __restrict__ X,
                                               us* __restrict__ Xt,
                                               int b, int c0, int n0, int t)
{
    __shared__ float T[64][65];

    const float* Xb = X + ((size_t)b * CC + c0) * LL + n0;
    #pragma unroll
    for (int i = 0; i < 4; ++i) {
        const int cl = (t >> 4) + 16 * i, nl = (t & 15) * 4;
        const float4 f = *(const float4*)(Xb + (size_t)cl * LL + nl);
        T[cl][nl + 0] = f.x; T[cl][nl + 1] = f.y;
        T[cl][nl + 2] = f.z; T[cl][nl + 3] = f.w;
    }
    __syncthreads();
    us* Ot = Xt + ((size_t)b * LL + n0) * CC + c0;
    #pragma unroll
    for (int i = 0; i < 2; ++i) {
        const int nl = (t >> 3) + 32 * i, cb = (t & 7) * 8;
        uint4v u;
        #pragma unroll
        for (int j = 0; j < 4; ++j)
            u[j] = pk2(T[cb + 2 * j][nl], T[cb + 2 * j + 1][nl]);
        *(bf16x8*)(Ot + (size_t)nl * CC + cb) = __builtin_bit_cast(bf16x8, u);
    }
}

__global__ __launch_bounds__(256) void transpose_cvt(const float* __restrict__ X,
                                                     us* __restrict__ Xt)
{
    transpose_body(X, Xt, blockIdx.z, blockIdx.y * 64, blockIdx.x * 64, threadIdx.x);
}

// fused: z = which*4 + b, which in {0:q, 1:k, 2:v}
__global__ __launch_bounds__(256) void transpose_cvt3(
    const float* __restrict__ Xq, const float* __restrict__ Xk,
    const float* __restrict__ Xv,
    us* __restrict__ X0, us* __restrict__ X1, us* __restrict__ X2)
{
    const int z = blockIdx.z, which = z >> 2, b = z & 3;
    const float* X = which == 0 ? Xq : (which == 1 ? Xk : Xv);
    us* Xt = which == 0 ? X0 : (which == 1 ? X1 : X2);
    transpose_body(X, Xt, b, blockIdx.y * 64, blockIdx.x * 64, threadIdx.x);
}

// ---------------------------------------------------------------------------
// fp32 -> bf16 for the four 512x512 weight matrices (one launch).
// ---------------------------------------------------------------------------
__global__ __launch_bounds__(256) void cvt_w4(const float* __restrict__ W0,
                                              const float* __restrict__ W1,
                                              const float* __restrict__ W2,
                                              const float* __restrict__ W3,
                                              us* __restrict__ out)
{
    const float* Ws[4] = {W0, W1, W2, W3};
    const float* W = Ws[blockIdx.y];
    us* O = out + (size_t)blockIdx.y * (CC * CC);
    const int i = (blockIdx.x * 256 + threadIdx.x) * 8;
    const float4 f0 = *(const float4*)(W + i);
    const float4 f1 = *(const float4*)(W + i + 4);
    uint4v u;
    u[0] = pk2(f0.x, f0.y); u[1] = pk2(f0.z, f0.w);
    u[2] = pk2(f1.x, f1.y); u[3] = pk2(f1.z, f1.w);
    *(bf16x8*)(O + i) = __builtin_bit_cast(bf16x8, u);
}

// ---------------------------------------------------------------------------
// GEMM core: Y[b][o][n] = sum_c W[o][c]*Xt[b][n][c] + bias[o].
// Block tile 128(M) x 128(N), BK=64, 256 thr = 4 waves in 2x2 (64x64/wave).
// Single-buffered LDS (A 16K + B 16K), staged by global_load_lds; tile
// layout [bk][row] 16B chunks (DMA-linear writes, contiguous half-wave
// reads). 2 barriers per K-step; 3 blocks/CU co-scheduling hides staging.
// mode 0: bf16 out, per-head position-major [b][h][n][64], (acc+bias)*scale
// mode 1: bf16 out, channel-major [b][o][n]
// mode 2: fp32 out, channel-major [b][o][n]
// ---------------------------------------------------------------------------
__device__ __forceinline__ void proj_body(const us* __restrict__ Xb,   // [n][c] for batch b
                                          const us* __restrict__ Wm,   // W rows m0..m0+127
                                          const float* __restrict__ bias,
                                          float scale, void* __restrict__ Yv,
                                          int b, int n0, int m0, int t, int mode)
{
    const int lane = t & 63, wave = t >> 6;
    const int quad2 = lane >> 5, l31 = lane & 31;
    const int wr = (wave >> 1) * 64, wc = (wave & 1) * 64;

    __shared__ __align__(16) char PS[32768];     // A [0,16384) | B [16384,32768)
    __shared__ float biasS[128];

    f32x16 acc[2][2];
    #pragma unroll
    for (int mi = 0; mi < 2; ++mi)
        #pragma unroll
        for (int ni = 0; ni < 2; ++ni)
            #pragma unroll
            for (int e = 0; e < 16; ++e) acc[mi][ni][e] = 0.f;

    if (t < 128) biasS[t] = bias[m0 + t];

    const int rdA = quad2 * 2048 + (wr + l31) * 16;
    const int rdB = 16384 + quad2 * 2048 + (wc + l31) * 16;

    for (int k0 = 0; k0 < CC; k0 += 64) {
        // stage: 16 segs x 64 chunks; seg covers [bk = seg>>1][rows (seg&1)*64+..]
        #pragma unroll
        for (int i = 0; i < 4; ++i) {
            const int sg = i * 4 + wave;
            const int r0 = (sg & 1) * 64, bk = sg >> 1;
            gl16(Wm + (size_t)(r0 + lane) * CC + k0 + bk * 8, PS + sg * 1024);
            gl16(Xb + (size_t)(n0 + r0 + lane) * CC + k0 + bk * 8,
                 PS + 16384 + sg * 1024);
        }
        __syncthreads();     // vmcnt drain: tile resident

        __builtin_amdgcn_s_setprio(1);
        #pragma unroll
        for (int ks = 0; ks < 4; ++ks) {
            const bf16x8 af0 = *(const bf16x8*)(PS + rdA + ks * 4096);
            const bf16x8 af1 = *(const bf16x8*)(PS + rdA + ks * 4096 + 512);
            const bf16x8 bf0 = *(const bf16x8*)(PS + rdB + ks * 4096);
            const bf16x8 bf1 = *(const bf16x8*)(PS + rdB + ks * 4096 + 512);
            acc[0][0] = __builtin_amdgcn_mfma_f32_32x32x16_bf16(af0, bf0, acc[0][0], 0, 0, 0);
            acc[0][1] = __builtin_amdgcn_mfma_f32_32x32x16_bf16(af0, bf1, acc[0][1], 0, 0, 0);
            acc[1][0] = __builtin_amdgcn_mfma_f32_32x32x16_bf16(af1, bf0, acc[1][0], 0, 0, 0);
            acc[1][1] = __builtin_amdgcn_mfma_f32_32x32x16_bf16(af1, bf1, acc[1][1], 0, 0, 0);
        }
        __builtin_amdgcn_s_setprio(0);
        __syncthreads();     // reads done before next staging
    }

    #pragma unroll
    for (int mi = 0; mi < 2; ++mi)
        #pragma unroll
        for (int ni = 0; ni < 2; ++ni) {
            const int nloc = wc + ni * 32 + l31;
            if (mode == 0) {
                us* Y = (us*)Yv;
                #pragma unroll
                for (int rg2 = 0; rg2 < 4; ++rg2) {
                    const int rbase = wr + mi * 32 + 8 * rg2 + 4 * quad2;
                    float v0 = (acc[mi][ni][rg2 * 4 + 0] + biasS[rbase + 0]) * scale;
                    float v1 = (acc[mi][ni][rg2 * 4 + 1] + biasS[rbase + 1]) * scale;
                    float v2 = (acc[mi][ni][rg2 * 4 + 2] + biasS[rbase + 2]) * scale;
                    float v3 = (acc[mi][ni][rg2 * 4 + 3] + biasS[rbase + 3]) * scale;
                    const int mg = m0 + rbase;
                    const int h = mg >> 6, d = mg & 63;
                    *(bf16x4*)(Y + (((size_t)(b * HH + h) * LL) + n0 + nloc) * DHH + d) =
                        pk4(v0, v1, v2, v3);
                }
            } else {
                #pragma unroll
                for (int reg = 0; reg < 16; ++reg) {
                    const int row = (reg & 3) + 8 * (reg >> 2) + 4 * quad2;
                    const int mloc = wr + mi * 32 + row;
                    const float v = (acc[mi][ni][reg] + biasS[mloc]) * scale;
                    const size_t addr = ((size_t)b * CC + m0 + mloc) * LL + n0 + nloc;
                    if (mode == 1) ((us*)Yv)[addr] = f2bu(v);
                    else           ((float*)Yv)[addr] = v;
                }
            }
        }
}

template <int MODE>
__global__ __launch_bounds__(256, 3) void proj_gemm(const us* __restrict__ Xt,
                                                    const us* __restrict__ Wb,
                                                    const float* __restrict__ bias,
                                                    float scale,
                                                    void* __restrict__ Yv)
{
    const int b = blockIdx.z, n0 = blockIdx.x * 128, m0 = blockIdx.y * 128;
    proj_body(Xt + (size_t)b * LL * CC, Wb + (size_t)m0 * CC, bias, scale, Yv,
              b, n0, m0, threadIdx.x, MODE);
}

// fused q/k/v projection: z = which*4 + b
__global__ __launch_bounds__(256, 3) void proj_gemm3(
    const us* __restrict__ X0, const us* __restrict__ X1, const us* __restrict__ X2,
    const us* __restrict__ Wb4,
    const float* __restrict__ bq, const float* __restrict__ bk,
    const float* __restrict__ bv, float scale_q,
    us* __restrict__ qh, us* __restrict__ kh, us* __restrict__ vh)
{
    const int z = blockIdx.z, which = z >> 2, b = z & 3;
    const int n0 = blockIdx.x * 128, m0 = blockIdx.y * 128;
    const us* Xt = which == 0 ? X0 : (which == 1 ? X1 : X2);
    const us* Wb = Wb4 + (size_t)which * (CC * CC);
    const float* bias = which == 0 ? bq : (which == 1 ? bk : bv);
    const float scale = which == 0 ? scale_q : 1.0f;
    us* Yv = which == 0 ? qh : (which == 1 ? kh : vh);
    const int mode = (which == 2) ? 1 : 0;
    proj_body(Xt + (size_t)b * LL * CC, Wb + (size_t)m0 * CC, bias, scale,
              (void*)Yv, b, n0, m0, threadIdx.x, mode);
}

// ---------------------------------------------------------------------------
// Flash attention, in-block KV-split x2. 512 thr = 8 waves; half = wave>>2.
// Waves 0-3: keys 0..1023, waves 4-7: keys 1024..2047, same 128 queries.
// Q staged once to LDS [bk][row] (16KB, shared). K and V double-buffered per
// half, staged by global_load_lds into [k-chunk][row] linear tiles (8KB each,
// DMA-linear writes + half-wave-contiguous reads: conflict-free, affine).
// exp2-direct softmax fused per-16-key group with its PV MFMAs (pfrag
// liveness 4 regs). Mask ballot from a one-tile-early global load.
// Halves merge linearly at the epilogue (O=O0+O1, l=l0+l1) via LDS.
// LDS: Q 16384 | K 2x(2x8192) | V 2x(2x8192) = 81920 B -> 2 blocks/CU.
// ---------------------------------------------------------------------------
__global__ __launch_bounds__(512, 4) void attn_fwd(
    const us* __restrict__ Qh,     // [b][h][l][64], pre-scaled
    const us* __restrict__ Kh,     // [b][h][l][64]
    const us* __restrict__ Vh,     // [b][512][l] channel-major
    const float* __restrict__ mask,// [b][1][L]
    us* __restrict__ ctx)          // [b][l][512]
{
    const int bh = blockIdx.x;     // 0..31
    const int b = bh >> 3, h = bh & 7;
    const int qb = blockIdx.y;     // 0..15
    const int t = threadIdx.x, lane = t & 63, wave = t >> 6;
    const int half = wave >> 2, wv = wave & 3;
    const int quad2 = lane >> 5, l31 = lane & 31;

    __shared__ __align__(16) char SM[81920];
    // Q [0,16384) | K(half)=16384+half*16384 (dbuf 2x8192)
    //             | V(half)=49152+half*16384 (dbuf 2x8192)

    const float* mb = mask + (size_t)b * LL;
    const int g0 = half * 16;                // first tile of this half

    // stage Q (128 q x 64 d) to LDS [bk][row]: chunk c = bk*128+row
    const us* Qg = Qh + ((size_t)bh * LL + qb * 128) * DHH;
    #pragma unroll
    for (int i = 0; i < 2; ++i) {
        const int c = t + i * 512, row = c & 127, bk = c >> 7;
        *(bf16x8*)(SM + c * 16) = *(const bf16x8*)(Qg + row * DHH + bk * 8);
    }

    const us* Kbase = Kh + (size_t)bh * LL * DHH;
    const us* Vbase = Vh + ((size_t)b * CC + h * DHH) * LL;
    char* KH = SM + 16384 + half * 16384;
    char* VH = SM + 49152 + half * 16384;

    // prologue: DMA tile g0 into buffer 0 (wave wv covers segs {wv, wv+4})
    {
        const int n1 = g0 * 64;
        #pragma unroll
        for (int i = 0; i < 2; ++i) {
            const int sg = i * 4 + wv;
            gl16(Kbase + (size_t)(n1 + lane) * DHH + sg * 8, KH + sg * 1024);
            gl16(Vbase + (size_t)lane * LL + n1 + sg * 8, VH + sg * 1024);
        }
    }
    float mval = mb[g0 * 64 + lane];         // mask value for tile g0
    __syncthreads();                         // Q staged + DMA drained

    f32x16 of[2];
    #pragma unroll
    for (int mt = 0; mt < 2; ++mt)
        #pragma unroll
        for (int e = 0; e < 16; ++e) of[mt][e] = 0.f;
    float l_run = 0.f;

    const int rdKV = quad2 * 1024 + l31 * 16;            // K/V fragment base
    const int qrd  = quad2 * 2048 + (wv * 32 + l31) * 16;// Q fragment base

    for (int itl = 0; itl < 16; ++itl) {
        const int cur = itl & 1;
        const char* Kc = KH + cur * 8192;
        const char* Vc = VH + cur * 8192;

        // async prefetch of tile itl+1 into the alternate buffers
        float mnext = 0.f;
        if (itl + 1 < 16) {
            const int n1 = (g0 + itl + 1) * 64;
            char* Kn = KH + (1 - cur) * 8192;
            char* Vn = VH + (1 - cur) * 8192;
            #pragma unroll
            for (int i = 0; i < 2; ++i) {
                const int sg = i * 4 + wv;
                gl16(Kbase + (size_t)(n1 + lane) * DHH + sg * 8, Kn + sg * 1024);
                gl16(Vbase + (size_t)lane * LL + n1 + sg * 8, Vn + sg * 1024);
            }
            mnext = mb[(size_t)(g0 + itl + 1) * 64 + lane];
        }

        // S^T = K^T Q
        f32x16 sf[2];
        #pragma unroll
        for (int mt = 0; mt < 2; ++mt)
            #pragma unroll
            for (int e = 0; e < 16; ++e) sf[mt][e] = 0.f;
        __builtin_amdgcn_s_setprio(1);
        #pragma unroll
        for (int ks = 0; ks < 4; ++ks) {
            const bf16x8 qk = *(const bf16x8*)(SM + qrd + ks * 4096);
            #pragma unroll
            for (int mt = 0; mt < 2; ++mt) {
                const bf16x8 af = *(const bf16x8*)(Kc + rdKV + ks * 2048 + mt * 512);
                sf[mt] = __builtin_amdgcn_mfma_f32_32x32x16_bf16(af, qk, sf[mt], 0, 0, 0);
            }
        }
        __builtin_amdgcn_s_setprio(0);

        // exp2-direct softmax, fused per 16-key group with its PV MFMAs
        const unsigned long long mw = __ballot(mval > 0.5f);
        const bool masked = (mw != 0xFFFFFFFFFFFFFFFFull);
        float ps = 0.f;
        #pragma unroll
        for (int j = 0; j < 4; ++j) {        // j = 2*mt + g; keys 16j..16j+16
            const int mt = j >> 1, g = j & 1;
            float p[8];
            #pragma unroll
            for (int el = 0; el < 8; ++el) p[el] = EXP2(sf[mt][8 * g + el]);
            if (masked) {
                #pragma unroll
                for (int el = 0; el < 8; ++el) {
                    const int row = 32 * mt + 16 * g + (el & 3) + 8 * (el >> 2) + 4 * quad2;
                    p[el] = ((mw >> row) & 1ull) ? p[el] : 0.f;
                }
            }
            ps += ((p[0] + p[1]) + (p[2] + p[3])) + ((p[4] + p[5]) + (p[6] + p[7]));
            // v_permlane32_swap_b32 vdst, vsrc:
            //   new_vdst = {lo: old_vdst.lo, hi: old_vsrc.lo}
            //   new_vsrc = {lo: old_vdst.hi, hi: old_vsrc.hi}
            // => vdst = low-n pair word (w0/w1), vsrc = +4 pair word (w2/w3).
            unsigned w0 = pk2(p[0], p[1]);
            unsigned w1 = pk2(p[2], p[3]);
            unsigned w2 = pk2(p[4], p[5]);
            unsigned w3 = pk2(p[6], p[7]);
            asm("v_permlane32_swap_b32 %0, %1" : "+v"(w0), "+v"(w2));
            asm("v_permlane32_swap_b32 %0, %1" : "+v"(w1), "+v"(w3));
            uint4v u; u[0] = w0; u[1] = w1; u[2] = w2; u[3] = w3;
            const bf16x8 pf = __builtin_bit_cast(bf16x8, u);
            __builtin_amdgcn_s_setprio(1);
            of[0] = __builtin_amdgcn_mfma_f32_32x32x16_bf16(
                *(const bf16x8*)(Vc + rdKV + j * 2048), pf, of[0], 0, 0, 0);
            of[1] = __builtin_amdgcn_mfma_f32_32x32x16_bf16(
                *(const bf16x8*)(Vc + rdKV + j * 2048 + 512), pf, of[1], 0, 0, 0);
            __builtin_amdgcn_s_setprio(0);
        }
        ps += __shfl_xor(ps, 32, 64);
        l_run += ps;
        mval = mnext;

        __syncthreads();   // drains prefetch DMA + all reads of buf[cur] done
    }

    // epilogue: merge halves (O = O0+O1, l = l0+l1), then ctx = O/l.
    // half1 parks partials in LDS (Q/K regions dead); half0 combines+writes.
    float4* OS = (float4*)SM;                // 4 wv x 8 chunks x 64 lanes = 32KB
    float*  LS = (float*)(SM + 32768);       // 4 wv x 64 lanes
    const int qg = qb * 128 + wv * 32;
    if (half == 1) {
        #pragma unroll
        for (int mt = 0; mt < 2; ++mt)
            #pragma unroll
            for (int r4 = 0; r4 < 4; ++r4) {
                float4 v;
                v.x = of[mt][r4 * 4 + 0]; v.y = of[mt][r4 * 4 + 1];
                v.z = of[mt][r4 * 4 + 2]; v.w = of[mt][r4 * 4 + 3];
                OS[(wv * 8 + mt * 4 + r4) * 64 + lane] = v;
            }
        LS[wv * 64 + lane] = l_run;
    }
    __syncthreads();
    if (half == 0) {
        l_run += LS[wv * 64 + lane];
        const float inv = 1.0f / l_run;
        us* Cb = ctx + (size_t)b * LL * CC;
        const int q = qg + l31;
        #pragma unroll
        for (int mt = 0; mt < 2; ++mt)
            #pragma unroll
            for (int r4 = 0; r4 < 4; ++r4) {
                const float4 v = OS[(wv * 8 + mt * 4 + r4) * 64 + lane];
                const int d = 32 * mt + 8 * r4 + 4 * quad2;
                *(bf16x4*)(Cb + (size_t)q * CC + h * DHH + d) =
                    pk4((of[mt][r4 * 4 + 0] + v.x) * inv,
                        (of[mt][r4 * 4 + 1] + v.y) * inv,
                        (of[mt][r4 * 4 + 2] + v.z) * inv,
                        (of[mt][r4 * 4 + 3] + v.w) * inv);
            }
    }
}

// ---------------------------------------------------------------------------
extern "C" void kernel_launch(void* const* d_in, const int* in_sizes, int n_in,
                              void* d_out, int out_size, void* d_ws, size_t ws_size,
                              hipStream_t stream)
{
    const float* q    = (const float*)d_in[0];
    const float* k    = (const float*)d_in[1];
    const float* v    = (const float*)d_in[2];
    const float* mask = (const float*)d_in[3];
    const float* Wq   = (const float*)d_in[4];
    const float* bq   = (const float*)d_in[5];
    const float* Wk   = (const float*)d_in[6];
    const float* bk   = (const float*)d_in[7];
    const float* Wv   = (const float*)d_in[8];
    const float* bv   = (const float*)d_in[9];
    const float* Wout = (const float*)d_in[10];
    const float* bout = (const float*)d_in[11];

    const size_t TSZ  = (size_t)BB * CC * LL;    // 4,194,304 elements (8 MB)
    const size_t WSZ  = (size_t)4 * CC * CC;     // 1,048,576 elements (2 MB)
    const float SCALE_Q = 0.125f * 1.4426950408889634f;  // softmax scale * log2e

    const dim3 tb(256), gb(256);

    if (ws_size >= (6 * TSZ + WSZ) * sizeof(us)) {
        // fused path: 5 launches
        us* X0  = (us*)d_ws;
        us* X1  = X0 + TSZ;
        us* X2  = X1 + TSZ;
        us* qh  = X2 + TSZ;
        us* kh  = qh + TSZ;
        us* vh  = kh + TSZ;
        us* Wb  = vh + TSZ;
        us* ctx = X0;                            // X0 dead after proj3

        cvt_w4<<<dim3(CC * CC / 2048, 4), tb, 0, stream>>>(Wq, Wk, Wv, Wout, Wb);
        transpose_cvt3<<<dim3(LL / 64, CC / 64, 12), tb, 0, stream>>>(q, k, v, X0, X1, X2);
        proj_gemm3<<<dim3(LL / 128, CC / 128, 12), gb, 0, stream>>>(
            X0, X1, X2, Wb, bq, bk, bv, SCALE_Q, qh, kh, vh);
        attn_fwd<<<dim3(HH * BB, LL / 128), dim3(512), 0, stream>>>(qh, kh, vh, mask, ctx);
        proj_gemm<2><<<dim3(LL / 128, CC / 128, BB), gb, 0, stream>>>(
            ctx, Wb + 3 * (size_t)CC * CC, bout, 1.0f, d_out);
    } else {
        // fallback: sequential path reusing one Xt buffer
        us* Xt  = (us*)d_ws;
        us* qh  = Xt + TSZ;
        us* kh  = qh + TSZ;
        us* vh  = kh + TSZ;
        us* Wb  = vh + TSZ;
        us* ctx = Xt;

        const dim3 tg(LL / 64, CC / 64, BB), gg(LL / 128, CC / 128, BB);

        cvt_w4<<<dim3(CC * CC / 2048, 4), tb, 0, stream>>>(Wq, Wk, Wv, Wout, Wb);
        transpose_cvt<<<tg, tb, 0, stream>>>(q, Xt);
        proj_gemm<0><<<gg, gb, 0, stream>>>(Xt, Wb + 0 * (size_t)CC * CC, bq, SCALE_Q, (void*)qh);
        transpose_cvt<<<tg, tb, 0, stream>>>(k, Xt);
        proj_gemm<0><<<gg, gb, 0, stream>>>(Xt, Wb + 1 * (size_t)CC * CC, bk, 1.0f, (void*)kh);
        transpose_cvt<<<tg, tb, 0, stream>>>(v, Xt);
        proj_gemm<1><<<gg, gb, 0, stream>>>(Xt, Wb + 2 * (size_t)CC * CC, bv, 1.0f, (void*)vh);
        attn_fwd<<<dim3(HH * BB, LL / 128), dim3(512), 0, stream>>>(qh, kh, vh, mask, ctx);
        proj_gemm<2><<<gg, gb, 0, stream>>>(ctx, Wb + 3 * (size_t)CC * CC, bout, 1.0f, d_out);
    }
}

// Round 8
// 201.880 us; speedup vs baseline: 1.0831x; 1.0831x over previous
//
#include <hip/hip_runtime.h>
#include <hip/hip_bf16.h>

// LocalAttention B=4, L=2048, C=512, H=8, Dh=64 — round 14.
// proj/transpose/launcher: round-10 versions (best measured total 192.5).
// attn: KV-split x2 (512 thr, 8 waves) with the register budget finally
// closed: per tile TWO 32-key passes (QK 4 MFMA -> softmax -> PV 4 MFMA),
// so sf is a single f32x16 (16 AGPR, was 32). Q in LDS; K/V staged by
// global_load_lds (no staging regs); per-16-key fused pack+PV (pfrag 4
// regs); incremental per-lane DMA pointers. Budget ~106 < 128 unified
// -> 4 waves/SIMD without spill (gate: WRITE_SIZE back to 8 MB).

#define BB  4
#define LL  2048
#define CC  512
#define HH  8
#define DHH 64

typedef __attribute__((ext_vector_type(8)))  short bf16x8;   // 16 B
typedef __attribute__((ext_vector_type(4)))  short bf16x4;   // 8 B
typedef __attribute__((ext_vector_type(16))) float f32x16;   // MFMA C/D
typedef __attribute__((ext_vector_type(2)))  unsigned uint2v;
typedef __attribute__((ext_vector_type(4)))  unsigned uint4v;

using us = unsigned short;

#if __has_builtin(__builtin_amdgcn_exp2f)
#define EXP2(x) __builtin_amdgcn_exp2f(x)
#else
#define EXP2(x) __expf(0.6931471805599453f * (x))
#endif

__device__ __forceinline__ int swz(int r) { return (r + (r >> 3)) & 7; }

__device__ __forceinline__ us f2bu(float x) {   // scalar fp32->bf16 (RNE)
    unsigned u = __float_as_uint(x);
    return (us)((u + 0x7FFFu + ((u >> 16) & 1u)) >> 16);
}
// HW packed fp32->bf16 (RNE), a -> low half, b -> high half
__device__ __forceinline__ unsigned pk2(float a, float b) {
    unsigned r;
    asm("v_cvt_pk_bf16_f32 %0, %1, %2" : "=v"(r) : "v"(a), "v"(b));
    return r;
}
__device__ __forceinline__ bf16x4 pk4(float a, float b, float c, float d) {
    uint2v u; u[0] = pk2(a, b); u[1] = pk2(c, d);
    return __builtin_bit_cast(bf16x4, u);
}

// async global->LDS DMA, 16B per lane; LDS dest = wave-uniform base + lane*16
__device__ __forceinline__ void gl16(const void* g, void* l) {
    __builtin_amdgcn_global_load_lds(
        (const __attribute__((address_space(1))) unsigned int*)g,
        (__attribute__((address_space(3))) unsigned int*)l, 16, 0, 0);
}

// ---------------------------------------------------------------------------
// transpose body: fp32 [b][c][n] -> bf16 [b][n][c] for one (b, c0, n0) tile
// ---------------------------------------------------------------------------
__device__ __forceinline__ void transpose_body(const float* __restrict__ X,
                                               us* __restrict__ Xt,
                                               int b, int c0, int n0, int t)
{
    __shared__ float T[64][65];

    const float* Xb = X + ((size_t)b * CC + c0) * LL + n0;
    #pragma unroll
    for (int i = 0; i < 4; ++i) {
        const int cl = (t >> 4) + 16 * i, nl = (t & 15) * 4;
        const float4 f = *(const float4*)(Xb + (size_t)cl * LL + nl);
        T[cl][nl + 0] = f.x; T[cl][nl + 1] = f.y;
        T[cl][nl + 2] = f.z; T[cl][nl + 3] = f.w;
    }
    __syncthreads();
    us* Ot = Xt + ((size_t)b * LL + n0) * CC + c0;
    #pragma unroll
    for (int i = 0; i < 2; ++i) {
        const int nl = (t >> 3) + 32 * i, cb = (t & 7) * 8;
        uint4v u;
        #pragma unroll
        for (int j = 0; j < 4; ++j)
            u[j] = pk2(T[cb + 2 * j][nl], T[cb + 2 * j + 1][nl]);
        *(bf16x8*)(Ot + (size_t)nl * CC + cb) = __builtin_bit_cast(bf16x8, u);
    }
}

__global__ __launch_bounds__(256) void transpose_cvt(const float* __restrict__ X,
                                                     us* __restrict__ Xt)
{
    transpose_body(X, Xt, blockIdx.z, blockIdx.y * 64, blockIdx.x * 64, threadIdx.x);
}

// fused: z = which*4 + b, which in {0:q, 1:k, 2:v}
__global__ __launch_bounds__(256) void transpose_cvt3(
    const float* __restrict__ Xq, const float* __restrict__ Xk,
    const float* __restrict__ Xv,
    us* __restrict__ X0, us* __restrict__ X1, us* __restrict__ X2)
{
    const int z = blockIdx.z, which = z >> 2, b = z & 3;
    const float* X = which == 0 ? Xq : (which == 1 ? Xk : Xv);
    us* Xt = which == 0 ? X0 : (which == 1 ? X1 : X2);
    transpose_body(X, Xt, b, blockIdx.y * 64, blockIdx.x * 64, threadIdx.x);
}

// ---------------------------------------------------------------------------
// fp32 -> bf16 for the four 512x512 weight matrices (one launch).
// ---------------------------------------------------------------------------
__global__ __launch_bounds__(256) void cvt_w4(const float* __restrict__ W0,
                                              const float* __restrict__ W1,
                                              const float* __restrict__ W2,
                                              const float* __restrict__ W3,
                                              us* __restrict__ out)
{
    const float* Ws[4] = {W0, W1, W2, W3};
    const float* W = Ws[blockIdx.y];
    us* O = out + (size_t)blockIdx.y * (CC * CC);
    const int i = (blockIdx.x * 256 + threadIdx.x) * 8;
    const float4 f0 = *(const float4*)(W + i);
    const float4 f1 = *(const float4*)(W + i + 4);
    uint4v u;
    u[0] = pk2(f0.x, f0.y); u[1] = pk2(f0.z, f0.w);
    u[2] = pk2(f1.x, f1.y); u[3] = pk2(f1.z, f1.w);
    *(bf16x8*)(O + i) = __builtin_bit_cast(bf16x8, u);
}

// ---------------------------------------------------------------------------
// GEMM core (round-10): Y[b][o][n] = sum_c W[o][c]*Xt[b][n][c] + bias[o].
// Block tile 128(M) x 128(N), BK=64, 256 thr = 4 waves in 2x2 (64x64/wave).
// Double-buffered LDS, register prefetch, 1 barrier per K-step.
// mode 0: bf16 out, per-head position-major [b][h][n][64], (acc+bias)*scale
// mode 1: bf16 out, channel-major [b][o][n]
// mode 2: fp32 out, channel-major [b][o][n]
// ---------------------------------------------------------------------------
__device__ __forceinline__ void proj_body(const us* __restrict__ Xb,   // [n][c] for batch b
                                          const us* __restrict__ Wm,   // W rows m0..m0+127
                                          const float* __restrict__ bias,
                                          float scale, void* __restrict__ Yv,
                                          int b, int n0, int m0, int t, int mode)
{
    const int lane = t & 63, wave = t >> 6;
    const int quad2 = lane >> 5, l31 = lane & 31;
    const int wr = (wave >> 1) * 64, wc = (wave & 1) * 64;

    __shared__ us As[2][128 * 64];   // [m][k] swizzled
    __shared__ us Bs[2][128 * 64];   // [n][k] swizzled
    __shared__ float biasS[128];

    f32x16 acc[2][2];
    #pragma unroll
    for (int mi = 0; mi < 2; ++mi)
        #pragma unroll
        for (int ni = 0; ni < 2; ++ni)
            #pragma unroll
            for (int e = 0; e < 16; ++e) acc[mi][ni][e] = 0.f;

    if (t < 128) biasS[t] = bias[m0 + t];

    // prologue: stage k-tile 0 into buffer 0
    #pragma unroll
    for (int i = 0; i < 4; ++i) {
        const int id = i * 256 + t, r = id >> 3, bk = id & 7;
        *(bf16x8*)(As[0] + r * 64 + ((bk ^ swz(r)) * 8)) =
            *(const bf16x8*)(Wm + (size_t)r * CC + bk * 8);
        *(bf16x8*)(Bs[0] + r * 64 + ((bk ^ swz(r)) * 8)) =
            *(const bf16x8*)(Xb + (size_t)(n0 + r) * CC + bk * 8);
    }
    __syncthreads();

    for (int it = 0; it < CC / 64; ++it) {
        const int cur = it & 1, k1 = (it + 1) * 64;

        bf16x8 apre[4], bpre[4];
        if (it + 1 < CC / 64) {
            #pragma unroll
            for (int i = 0; i < 4; ++i) {
                const int id = i * 256 + t, r = id >> 3, bk = id & 7;
                apre[i] = *(const bf16x8*)(Wm + (size_t)r * CC + k1 + bk * 8);
                bpre[i] = *(const bf16x8*)(Xb + (size_t)(n0 + r) * CC + k1 + bk * 8);
            }
        }

        __builtin_amdgcn_s_setprio(1);
        #pragma unroll
        for (int ks = 0; ks < 4; ++ks) {
            const int bk = quad2 + 2 * ks;
            const int ra0 = wr + l31, ra1 = ra0 + 32;
            const int rb0 = wc + l31, rb1 = rb0 + 32;
            const bf16x8 af0 = *(const bf16x8*)(As[cur] + ra0 * 64 + ((bk ^ swz(ra0)) * 8));
            const bf16x8 af1 = *(const bf16x8*)(As[cur] + ra1 * 64 + ((bk ^ swz(ra1)) * 8));
            const bf16x8 bf0 = *(const bf16x8*)(Bs[cur] + rb0 * 64 + ((bk ^ swz(rb0)) * 8));
            const bf16x8 bf1 = *(const bf16x8*)(Bs[cur] + rb1 * 64 + ((bk ^ swz(rb1)) * 8));
            acc[0][0] = __builtin_amdgcn_mfma_f32_32x32x16_bf16(af0, bf0, acc[0][0], 0, 0, 0);
            acc[0][1] = __builtin_amdgcn_mfma_f32_32x32x16_bf16(af0, bf1, acc[0][1], 0, 0, 0);
            acc[1][0] = __builtin_amdgcn_mfma_f32_32x32x16_bf16(af1, bf0, acc[1][0], 0, 0, 0);
            acc[1][1] = __builtin_amdgcn_mfma_f32_32x32x16_bf16(af1, bf1, acc[1][1], 0, 0, 0);
        }
        __builtin_amdgcn_s_setprio(0);

        if (it + 1 < CC / 64) {
            #pragma unroll
            for (int i = 0; i < 4; ++i) {
                const int id = i * 256 + t, r = id >> 3, bk = id & 7;
                *(bf16x8*)(As[1 - cur] + r * 64 + ((bk ^ swz(r)) * 8)) = apre[i];
                *(bf16x8*)(Bs[1 - cur] + r * 64 + ((bk ^ swz(r)) * 8)) = bpre[i];
            }
        }
        __syncthreads();
    }

    #pragma unroll
    for (int mi = 0; mi < 2; ++mi)
        #pragma unroll
        for (int ni = 0; ni < 2; ++ni) {
            const int nloc = wc + ni * 32 + l31;
            if (mode == 0) {
                us* Y = (us*)Yv;
                #pragma unroll
                for (int rg2 = 0; rg2 < 4; ++rg2) {
                    const int rbase = wr + mi * 32 + 8 * rg2 + 4 * quad2;
                    float v0 = (acc[mi][ni][rg2 * 4 + 0] + biasS[rbase + 0]) * scale;
                    float v1 = (acc[mi][ni][rg2 * 4 + 1] + biasS[rbase + 1]) * scale;
                    float v2 = (acc[mi][ni][rg2 * 4 + 2] + biasS[rbase + 2]) * scale;
                    float v3 = (acc[mi][ni][rg2 * 4 + 3] + biasS[rbase + 3]) * scale;
                    const int mg = m0 + rbase;
                    const int h = mg >> 6, d = mg & 63;
                    *(bf16x4*)(Y + (((size_t)(b * HH + h) * LL) + n0 + nloc) * DHH + d) =
                        pk4(v0, v1, v2, v3);
                }
            } else {
                #pragma unroll
                for (int reg = 0; reg < 16; ++reg) {
                    const int row = (reg & 3) + 8 * (reg >> 2) + 4 * quad2;
                    const int mloc = wr + mi * 32 + row;
                    const float v = (acc[mi][ni][reg] + biasS[mloc]) * scale;
                    const size_t addr = ((size_t)b * CC + m0 + mloc) * LL + n0 + nloc;
                    if (mode == 1) ((us*)Yv)[addr] = f2bu(v);
                    else           ((float*)Yv)[addr] = v;
                }
            }
        }
}

template <int MODE>
__global__ __launch_bounds__(256, 2) void proj_gemm(const us* __restrict__ Xt,
                                                    const us* __restrict__ Wb,
                                                    const float* __restrict__ bias,
                                                    float scale,
                                                    void* __restrict__ Yv)
{
    const int b = blockIdx.z, n0 = blockIdx.x * 128, m0 = blockIdx.y * 128;
    proj_body(Xt + (size_t)b * LL * CC, Wb + (size_t)m0 * CC, bias, scale, Yv,
              b, n0, m0, threadIdx.x, MODE);
}

// fused q/k/v projection: z = which*4 + b
__global__ __launch_bounds__(256, 2) void proj_gemm3(
    const us* __restrict__ X0, const us* __restrict__ X1, const us* __restrict__ X2,
    const us* __restrict__ Wb4,
    const float* __restrict__ bq, const float* __restrict__ bk,
    const float* __restrict__ bv, float scale_q,
    us* __restrict__ qh, us* __restrict__ kh, us* __restrict__ vh)
{
    const int z = blockIdx.z, which = z >> 2, b = z & 3;
    const int n0 = blockIdx.x * 128, m0 = blockIdx.y * 128;
    const us* Xt = which == 0 ? X0 : (which == 1 ? X1 : X2);
    const us* Wb = Wb4 + (size_t)which * (CC * CC);
    const float* bias = which == 0 ? bq : (which == 1 ? bk : bv);
    const float scale = which == 0 ? scale_q : 1.0f;
    us* Yv = which == 0 ? qh : (which == 1 ? kh : vh);
    const int mode = (which == 2) ? 1 : 0;
    proj_body(Xt + (size_t)b * LL * CC, Wb + (size_t)m0 * CC, bias, scale,
              (void*)Yv, b, n0, m0, threadIdx.x, mode);
}

// ---------------------------------------------------------------------------
// Flash attention, in-block KV-split x2, register-lean. 512 thr = 8 waves;
// half = wave>>2: waves 0-3 keys 0..1023, waves 4-7 keys 1024..2047, same
// 128 queries. Q staged once to LDS [bk][q] (16KB shared). K/V double-
// buffered per half via global_load_lds ([chunk][row] linear tiles, DMA-
// linear writes + contiguous half-wave reads, affine offset:imm).
// Per tile: TWO 32-key passes {QK 4 MFMA -> softmax -> PV 4 MFMA}: sf is a
// single f32x16 (16 AGPR). exp2-direct softmax; per-16-key fused pack+PV
// (pfrag liveness 4 regs). Incremental per-lane DMA pointers.
// Halves merge linearly at the epilogue (O=O0+O1, l=l0+l1) via LDS.
// LDS: Q 16384 | K 2x(2x8192) | V 2x(2x8192) = 81920 B -> 2 blocks/CU.
// Unified regs ~106 < 128 -> 4 waves/SIMD, no spill.
// ---------------------------------------------------------------------------
__global__ __launch_bounds__(512, 4) void attn_fwd(
    const us* __restrict__ Qh,     // [b][h][l][64], pre-scaled
    const us* __restrict__ Kh,     // [b][h][l][64]
    const us* __restrict__ Vh,     // [b][512][l] channel-major
    const float* __restrict__ mask,// [b][1][L]
    us* __restrict__ ctx)          // [b][l][512]
{
    const int bh = blockIdx.x;     // 0..31
    const int b = bh >> 3, h = bh & 7;
    const int qb = blockIdx.y;     // 0..15
    const int t = threadIdx.x, lane = t & 63, wave = t >> 6;
    const int half = wave >> 2, wv = wave & 3;
    const int quad2 = lane >> 5, l31 = lane & 31;

    __shared__ __align__(16) char SM[81920];
    // Q [0,16384) | K(half)=16384+half*16384 (dbuf 2x8192)
    //             | V(half)=49152+half*16384 (dbuf 2x8192)

    const float* mb = mask + (size_t)b * LL;
    const int g0 = half * 16;                // first tile of this half

    // stage Q (128 q x 64 d) to LDS [bk][q]: chunk c = bk*128 + q
    const us* Qg = Qh + ((size_t)bh * LL + qb * 128) * DHH;
    #pragma unroll
    for (int i = 0; i < 2; ++i) {
        const int c = t + i * 512, row = c & 127, bk = c >> 7;
        *(bf16x8*)(SM + c * 16) = *(const bf16x8*)(Qg + row * DHH + bk * 8);
    }

    char* KH = SM + 16384 + half * 16384;
    char* VH = SM + 49152 + half * 16384;

    // incremental per-lane global pointers (wave wv covers chunks wv, wv+4)
    const us* kp = Kh + (size_t)bh * LL * DHH + ((size_t)(g0 * 64) + lane) * DHH + wv * 8;
    const us* vp = Vh + ((size_t)b * CC + h * DHH) * LL + (size_t)lane * LL + g0 * 64 + wv * 8;
    const float* mp = mb + g0 * 64 + lane;

    // prologue: DMA tile g0 into buffer 0
    gl16(kp,      KH + wv * 1024);
    gl16(kp + 32, KH + (wv + 4) * 1024);
    gl16(vp,      VH + wv * 1024);
    gl16(vp + 32, VH + (wv + 4) * 1024);
    kp += 64 * DHH; vp += 64;
    float mval = *mp; mp += 64;
    __syncthreads();                         // Q staged + DMA drained

    f32x16 of[2];
    #pragma unroll
    for (int mt = 0; mt < 2; ++mt)
        #pragma unroll
        for (int e = 0; e < 16; ++e) of[mt][e] = 0.f;
    float l_run = 0.f;

    const int rdKV = quad2 * 1024 + l31 * 16;             // K/V fragment base
    const int qrd  = quad2 * 2048 + (wv * 32 + l31) * 16; // Q fragment base

    for (int itl = 0; itl < 16; ++itl) {
        const int cur = itl & 1;
        const char* Kc = KH + cur * 8192;
        const char* Vc = VH + cur * 8192;

        // async prefetch of tile itl+1 into the alternate buffers
        float mnext = 0.f;
        if (itl + 1 < 16) {
            char* Kn = KH + (1 - cur) * 8192;
            char* Vn = VH + (1 - cur) * 8192;
            gl16(kp,      Kn + wv * 1024);
            gl16(kp + 32, Kn + (wv + 4) * 1024);
            gl16(vp,      Vn + wv * 1024);
            gl16(vp + 32, Vn + (wv + 4) * 1024);
            kp += 64 * DHH; vp += 64;
            mnext = *mp; mp += 64;
        }

        const unsigned long long mw = __ballot(mval > 0.5f);
        const bool masked = (mw != 0xFFFFFFFFFFFFFFFFull);
        float ps = 0.f;

        // two 32-key passes: sf lives only within a pass (16 AGPR)
        #pragma unroll
        for (int mt = 0; mt < 2; ++mt) {
            f32x16 sf;
            #pragma unroll
            for (int e = 0; e < 16; ++e) sf[e] = 0.f;
            __builtin_amdgcn_s_setprio(1);
            #pragma unroll
            for (int ks = 0; ks < 4; ++ks) {
                const bf16x8 qk = *(const bf16x8*)(SM + qrd + ks * 4096);
                const bf16x8 af = *(const bf16x8*)(Kc + rdKV + ks * 2048 + mt * 512);
                sf = __builtin_amdgcn_mfma_f32_32x32x16_bf16(af, qk, sf, 0, 0, 0);
            }
            __builtin_amdgcn_s_setprio(0);

            #pragma unroll
            for (int g = 0; g < 2; ++g) {    // keys 32mt+16g .. +15
                float p[8];
                #pragma unroll
                for (int el = 0; el < 8; ++el) p[el] = EXP2(sf[8 * g + el]);
                if (masked) {
                    #pragma unroll
                    for (int el = 0; el < 8; ++el) {
                        const int row = 32 * mt + 16 * g + (el & 3) + 8 * (el >> 2) + 4 * quad2;
                        p[el] = ((mw >> row) & 1ull) ? p[el] : 0.f;
                    }
                }
                ps += ((p[0] + p[1]) + (p[2] + p[3])) + ((p[4] + p[5]) + (p[6] + p[7]));
                // v_permlane32_swap_b32 vdst, vsrc:
                //   new_vdst = {lo: old_vdst.lo, hi: old_vsrc.lo}
                //   new_vsrc = {lo: old_vdst.hi, hi: old_vsrc.hi}
                // => vdst = low-n pair word (w0/w1), vsrc = +4 pair (w2/w3).
                unsigned w0 = pk2(p[0], p[1]);
                unsigned w1 = pk2(p[2], p[3]);
                unsigned w2 = pk2(p[4], p[5]);
                unsigned w3 = pk2(p[6], p[7]);
                asm("v_permlane32_swap_b32 %0, %1" : "+v"(w0), "+v"(w2));
                asm("v_permlane32_swap_b32 %0, %1" : "+v"(w1), "+v"(w3));
                uint4v u; u[0] = w0; u[1] = w1; u[2] = w2; u[3] = w3;
                const bf16x8 pf = __builtin_bit_cast(bf16x8, u);
                const int j = 2 * mt + g;
                __builtin_amdgcn_s_setprio(1);
                of[0] = __builtin_amdgcn_mfma_f32_32x32x16_bf16(
                    *(const bf16x8*)(Vc + rdKV + j * 2048), pf, of[0], 0, 0, 0);
                of[1] = __builtin_amdgcn_mfma_f32_32x32x16_bf16(
                    *(const bf16x8*)(Vc + rdKV + j * 2048 + 512), pf, of[1], 0, 0, 0);
                __builtin_amdgcn_s_setprio(0);
            }
        }
        ps += __shfl_xor(ps, 32, 64);
        l_run += ps;
        mval = mnext;

        __syncthreads();   // drains prefetch DMA; all reads of buf[cur] done
    }

    // epilogue: merge halves (O = O0+O1, l = l0+l1), then ctx = O/l.
    // half1 parks partials in LDS (Q/K regions dead); half0 combines+writes.
    float4* OS = (float4*)SM;                // 4 wv x 8 chunks x 64 lanes = 32KB
    float*  LS = (float*)(SM + 32768);       // 4 wv x 64 lanes
    const int qg = qb * 128 + wv * 32;
    if (half == 1) {
        #pragma unroll
        for (int mt = 0; mt < 2; ++mt)
            #pragma unroll
            for (int r4 = 0; r4 < 4; ++r4) {
                float4 v;
                v.x = of[mt][r4 * 4 + 0]; v.y = of[mt][r4 * 4 + 1];
                v.z = of[mt][r4 * 4 + 2]; v.w = of[mt][r4 * 4 + 3];
                OS[(wv * 8 + mt * 4 + r4) * 64 + lane] = v;
            }
        LS[wv * 64 + lane] = l_run;
    }
    __syncthreads();
    if (half == 0) {
        l_run += LS[wv * 64 + lane];
        const float inv = 1.0f / l_run;
        us* Cb = ctx + (size_t)b * LL * CC;
        const int q = qg + l31;
        #pragma unroll
        for (int mt = 0; mt < 2; ++mt)
            #pragma unroll
            for (int r4 = 0; r4 < 4; ++r4) {
                const float4 v = OS[(wv * 8 + mt * 4 + r4) * 64 + lane];
                const int d = 32 * mt + 8 * r4 + 4 * quad2;
                *(bf16x4*)(Cb + (size_t)q * CC + h * DHH + d) =
                    pk4((of[mt][r4 * 4 + 0] + v.x) * inv,
                        (of[mt][r4 * 4 + 1] + v.y) * inv,
                        (of[mt][r4 * 4 + 2] + v.z) * inv,
                        (of[mt][r4 * 4 + 3] + v.w) * inv);
            }
    }
}

// ---------------------------------------------------------------------------
extern "C" void kernel_launch(void* const* d_in, const int* in_sizes, int n_in,
                              void* d_out, int out_size, void* d_ws, size_t ws_size,
                              hipStream_t stream)
{
    const float* q    = (const float*)d_in[0];
    const float* k    = (const float*)d_in[1];
    const float* v    = (const float*)d_in[2];
    const float* mask = (const float*)d_in[3];
    const float* Wq   = (const float*)d_in[4];
    const float* bq   = (const float*)d_in[5];
    const float* Wk   = (const float*)d_in[6];
    const float* bk   = (const float*)d_in[7];
    const float* Wv   = (const float*)d_in[8];
    const float* bv   = (const float*)d_in[9];
    const float* Wout = (const float*)d_in[10];
    const float* bout = (const float*)d_in[11];

    const size_t TSZ  = (size_t)BB * CC * LL;    // 4,194,304 elements (8 MB)
    const size_t WSZ  = (size_t)4 * CC * CC;     // 1,048,576 elements (2 MB)
    const float SCALE_Q = 0.125f * 1.4426950408889634f;  // softmax scale * log2e

    const dim3 tb(256), gb(256);

    if (ws_size >= (6 * TSZ + WSZ) * sizeof(us)) {
        // fused path: 5 launches
        us* X0  = (us*)d_ws;
        us* X1  = X0 + TSZ;
        us* X2  = X1 + TSZ;
        us* qh  = X2 + TSZ;
        us* kh  = qh + TSZ;
        us* vh  = kh + TSZ;
        us* Wb  = vh + TSZ;
        us* ctx = X0;                            // X0 dead after proj3

        cvt_w4<<<dim3(CC * CC / 2048, 4), tb, 0, stream>>>(Wq, Wk, Wv, Wout, Wb);
        transpose_cvt3<<<dim3(LL / 64, CC / 64, 12), tb, 0, stream>>>(q, k, v, X0, X1, X2);
        proj_gemm3<<<dim3(LL / 128, CC / 128, 12), gb, 0, stream>>>(
            X0, X1, X2, Wb, bq, bk, bv, SCALE_Q, qh, kh, vh);
        attn_fwd<<<dim3(HH * BB, LL / 128), dim3(512), 0, stream>>>(qh, kh, vh, mask, ctx);
        proj_gemm<2><<<dim3(LL / 128, CC / 128, BB), gb, 0, stream>>>(
            ctx, Wb + 3 * (size_t)CC * CC, bout, 1.0f, d_out);
    } else {
        // fallback: sequential path reusing one Xt buffer
        us* Xt  = (us*)d_ws;
        us* qh  = Xt + TSZ;
        us* kh  = qh + TSZ;
        us* vh  = kh + TSZ;
        us* Wb  = vh + TSZ;
        us* ctx = Xt;

        const dim3 tg(LL / 64, CC / 64, BB), gg(LL / 128, CC / 128, BB);

        cvt_w4<<<dim3(CC * CC / 2048, 4), tb, 0, stream>>>(Wq, Wk, Wv, Wout, Wb);
        transpose_cvt<<<tg, tb, 0, stream>>>(q, Xt);
        proj_gemm<0><<<gg, gb, 0, stream>>>(Xt, Wb + 0 * (size_t)CC * CC, bq, SCALE_Q, (void*)qh);
        transpose_cvt<<<tg, tb, 0, stream>>>(k, Xt);
        proj_gemm<0><<<gg, gb, 0, stream>>>(Xt, Wb + 1 * (size_t)CC * CC, bk, 1.0f, (void*)kh);
        transpose_cvt<<<tg, tb, 0, stream>>>(v, Xt);
        proj_gemm<1><<<gg, gb, 0, stream>>>(Xt, Wb + 2 * (size_t)CC * CC, bv, 1.0f, (void*)vh);
        attn_fwd<<<dim3(HH * BB, LL / 128), dim3(512), 0, stream>>>(qh, kh, vh, mask, ctx);
        proj_gemm<2><<<gg, gb, 0, stream>>>(ctx, Wb + 3 * (size_t)CC * CC, bout, 1.0f, d_out);
    }
}